// Round 8
// baseline (27.030 us; speedup 1.0000x reference)
//
#include <hip/hip_runtime.h>

// Tree positional embedding, closed form:
//   out[i][8*j + child_idx(ancestor_j(i))] = 1.0 for j < min(depth[i], K), else 0
// BRANCH=8, K_DEPTH=16 (h = 128 floats/row).
//
// Two-kernel split:
//   A (walk): one thread per row; walks the parent chain; packs one 4-bit
//     field per level (child_idx 0..7 if level < depth, sentinel 8 otherwise)
//     into a u64 code -> d_ws[row]. 1.6 MB coalesced write, ~2us.
//   B (expand): one thread per float4 chunk (N*32 threads, exactly
//     fill-kernel-shaped: uniform, sync-free). Reads the row code (8 B,
//     L1-broadcast across the 32 chunk-threads of the row, which live in one
//     half-wave), extracts the hot column, emits one coalesced dwordx4 store.
//     No barriers, no dependent chains -> should stream at fill rate.
// Fallback: if ws_size < N*8, use the fused R3-style kernel instead
// (host-side branch on launch constants -> graph-safe, deterministic).

#define PE_K 16

typedef float vf4 __attribute__((ext_vector_type(4)));

__global__ __launch_bounds__(256) void pe_walk_kernel(
    const int* __restrict__ parent,
    const int* __restrict__ child_idx,
    const int* __restrict__ depth,
    unsigned long long* __restrict__ codes,
    int N) {
  int row = blockIdx.x * 256 + threadIdx.x;
  if (row >= N) return;
  unsigned long long code = 0x8888888888888888ULL;  // sentinel 8 everywhere
  int d  = depth[row];
  int dd = d < PE_K ? d : PE_K;
  int cur = row;
  for (int j = 0; j < dd; ++j) {
    unsigned long long ci = (unsigned long long)(child_idx[cur] & 7);
    code = (code & ~(0xFULL << (4 * j))) | (ci << (4 * j));
    cur = parent[cur];
  }
  codes[row] = code;
}

__global__ __launch_bounds__(256) void pe_expand_kernel(
    const unsigned long long* __restrict__ codes,
    float* __restrict__ out,
    long long total_chunks) {
  long long gid = (long long)blockIdx.x * 256 + threadIdx.x;
  if (gid >= total_chunks) return;
  int c = (int)(gid & 31);            // float4 chunk within row
  long long row = gid >> 5;
  int j  = c >> 1;                    // 8-wide level slot
  int r0 = 4 * c - 8 * j;             // compare window base: 0 or 4

  unsigned long long code = codes[row];
  int ci = (int)((code >> (4 * j)) & 15);   // 0..7 hot child, 8 = none

  vf4 v;
  v.x = (ci == r0 + 0) ? 1.f : 0.f;
  v.y = (ci == r0 + 1) ? 1.f : 0.f;
  v.z = (ci == r0 + 2) ? 1.f : 0.f;
  v.w = (ci == r0 + 3) ? 1.f : 0.f;

  reinterpret_cast<vf4*>(out)[gid] = v;
}

// ---- fallback: fused R3 kernel (best single-kernel variant, 21.6us) ----
#define ROWS_PER_BLOCK 128
__global__ __launch_bounds__(256) void pe_fused_kernel(
    const int* __restrict__ parent,
    const int* __restrict__ child_idx,
    const int* __restrict__ depth,
    float* __restrict__ out,
    int N) {
  __shared__ unsigned long long codes[ROWS_PER_BLOCK];
  const int tid  = threadIdx.x;
  const int row0 = blockIdx.x * ROWS_PER_BLOCK;
  if (tid < ROWS_PER_BLOCK) {
    int row = row0 + tid;
    unsigned long long code = 0;
    if (row < N) {
      int d  = depth[row];
      int dd = d < PE_K ? d : PE_K;
      int cur = row;
      for (int j = 0; j < dd; ++j) {
        int ci = child_idx[cur] & 7;
        code |= (unsigned long long)ci << (3 * j);
        cur = parent[cur];
      }
      code |= (unsigned long long)dd << 48;
    }
    codes[tid] = code;
  }
  __syncthreads();
  const int c  = tid & 31;
  const int g  = tid >> 5;
  const int j  = c >> 1;
  const int sh = 3 * j;
  const int r0 = 4 * c - 8 * j;
  vf4* p = reinterpret_cast<vf4*>(out) + ((long long)(row0 + g) * 32 + c);
  const int last_full_rl = N - row0;
  #pragma unroll
  for (int it = 0; it < ROWS_PER_BLOCK / 8; ++it) {
    int rl = it * 8 + g;
    unsigned long long code = codes[rl];
    int dd = (int)(code >> 48);
    int ci = (int)((code >> sh) & 7);
    ci = (j < dd) ? ci : 8;
    vf4 v;
    v.x = (ci == r0 + 0) ? 1.f : 0.f;
    v.y = (ci == r0 + 1) ? 1.f : 0.f;
    v.z = (ci == r0 + 2) ? 1.f : 0.f;
    v.w = (ci == r0 + 3) ? 1.f : 0.f;
    if (rl < last_full_rl) *p = v;
    p += 8 * 32;
  }
}

extern "C" void kernel_launch(void* const* d_in, const int* in_sizes, int n_in,
                              void* d_out, int out_size, void* d_ws, size_t ws_size,
                              hipStream_t stream) {
  const int* parent    = (const int*)d_in[0];
  const int* child_idx = (const int*)d_in[1];
  const int* depth     = (const int*)d_in[2];
  // d_in[3] = p_emb (unused), d_in[4] = n (=8), d_in[5] = k (=16)
  float* out = (float*)d_out;
  int N = in_sizes[0];

  if (ws_size >= (size_t)N * 8) {
    unsigned long long* codes = (unsigned long long*)d_ws;
    int gridA = (N + 255) / 256;                       // 782
    pe_walk_kernel<<<gridA, 256, 0, stream>>>(parent, child_idx, depth, codes, N);
    long long total_chunks = (long long)N * 32;        // 6.4M
    int gridB = (int)((total_chunks + 255) / 256);     // 25000
    pe_expand_kernel<<<gridB, 256, 0, stream>>>(codes, out, total_chunks);
  } else {
    int grid = (N + ROWS_PER_BLOCK - 1) / ROWS_PER_BLOCK;
    pe_fused_kernel<<<grid, 256, 0, stream>>>(parent, child_idx, depth, out, N);
  }
}

// Round 9
// 21.501 us; speedup vs baseline: 1.2571x; 1.2571x over previous
//
#include <hip/hip_runtime.h>

// Tree positional embedding, closed form:
//   out[i][8*j + child_idx(ancestor_j(i))] = 1.0 for j < min(depth[i], K), else 0
// BRANCH=8, K_DEPTH=16 (h = 128 floats/row).
//
// FINAL (= R3, best of 8 variants at 21.6us):
// Block = 256 threads, 128 rows (64 KB of output).
//   Phase 1: threads 0..127 each walk one row's parent chain (coalesced
//            gathers, ancestors of adjacent rows share cachelines), pack hot
//            columns (3 bits/level) + clamped depth into a u64 code in LDS.
//   Phase 2: per-thread constants: c = tid&31 (float4 chunk), j = c>>1 (slot),
//            shift = 3j, window base r0 = 4c-8j in {0,4}. 16 unrolled
//            iterations: LDS code read (broadcast), extract child index
//            (or sentinel 8 if j >= depth), 4 cmp/cndmask -> float4, one
//            coalesced dwordx4 store.
//
// Perf accounting (measured over R0-R8):
//   102.4 MB mandatory write / 6.88 TB/s measured fill ceiling = 14.9 us
//   + ~5 us harness/launch fixed floor (isolated via 2-kernel split: +5.4 us)
//   + ~1.7 us walk prologue/barrier (inside fill noise band +-1.4 us)
//   = 21.6 us observed. Store-bandwidth roofline.
// Rejected by experiment: nontemporal stores (+2..4 us), shfl instead of LDS
// (+0.6), 256-row tiles (+1.4), barrier-free wave-autonomous (+0.6), two-
// kernel walk/expand split (+5.4).

#define PE_K 16
#define ROWS_PER_BLOCK 128

typedef float vf4 __attribute__((ext_vector_type(4)));

__global__ __launch_bounds__(256) void PositionalEmbedding_kernel(
    const int* __restrict__ parent,
    const int* __restrict__ child_idx,
    const int* __restrict__ depth,
    float* __restrict__ out,
    int N) {
  __shared__ unsigned long long codes[ROWS_PER_BLOCK];

  const int tid  = threadIdx.x;
  const int row0 = blockIdx.x * ROWS_PER_BLOCK;

  // ---- Phase 1: one lane per row builds the packed ancestor code ----
  if (tid < ROWS_PER_BLOCK) {
    int row = row0 + tid;
    unsigned long long code = 0;
    if (row < N) {
      int d  = depth[row];
      int dd = d < PE_K ? d : PE_K;
      int cur = row;
      for (int j = 0; j < dd; ++j) {
        int ci = child_idx[cur] & 7;
        code |= (unsigned long long)ci << (3 * j);
        cur = parent[cur];
      }
      code |= (unsigned long long)dd << 48;
    }
    codes[tid] = code;
  }
  __syncthreads();

  // ---- Phase 2: stream 128 rows x 32 float4, all constants hoisted ----
  const int c  = tid & 31;        // float4 chunk within row (constant)
  const int g  = tid >> 5;        // row-group 0..7 (constant)
  const int j  = c >> 1;          // 8-wide level slot (constant)
  const int sh = 3 * j;           // code shift (constant)
  const int r0 = 4 * c - 8 * j;   // compare window base: 0 or 4 (constant)

  vf4* p = reinterpret_cast<vf4*>(out) + ((long long)(row0 + g) * 32 + c);
  const int last_full_rl = N - row0;   // rows with rl < this are valid

  #pragma unroll
  for (int it = 0; it < ROWS_PER_BLOCK / 8; ++it) {
    int rl = it * 8 + g;
    unsigned long long code = codes[rl];
    int dd = (int)(code >> 48);
    int ci = (int)((code >> sh) & 7);
    ci = (j < dd) ? ci : 8;            // 8 = matches nothing -> zeros

    vf4 v;
    v.x = (ci == r0 + 0) ? 1.f : 0.f;
    v.y = (ci == r0 + 1) ? 1.f : 0.f;
    v.z = (ci == r0 + 2) ? 1.f : 0.f;
    v.w = (ci == r0 + 3) ? 1.f : 0.f;

    if (rl < last_full_rl) *p = v;     // only the last block is ever partial
    p += 8 * 32;                       // advance 8 rows
  }
}

extern "C" void kernel_launch(void* const* d_in, const int* in_sizes, int n_in,
                              void* d_out, int out_size, void* d_ws, size_t ws_size,
                              hipStream_t stream) {
  const int* parent    = (const int*)d_in[0];
  const int* child_idx = (const int*)d_in[1];
  const int* depth     = (const int*)d_in[2];
  // d_in[3] = p_emb (unused), d_in[4] = n (=8), d_in[5] = k (=16)
  float* out = (float*)d_out;
  int N = in_sizes[0];

  int grid = (N + ROWS_PER_BLOCK - 1) / ROWS_PER_BLOCK;   // 1563 @ N=200k
  PositionalEmbedding_kernel<<<grid, 256, 0, stream>>>(parent, child_idx, depth, out, N);
}